// Round 8
// baseline (125.498 us; speedup 1.0000x reference)
//
#include <hip/hip_runtime.h>
#include <hip/hip_bf16.h>

typedef __attribute__((ext_vector_type(8))) __bf16 bf16x8;
typedef __attribute__((ext_vector_type(4))) float f32x4;
typedef unsigned short u16;

#define CIN   62
#define HW    224
#define NPIX  49

__device__ __forceinline__ u16 f2b(float f) {
    union { __hip_bfloat16 h; u16 u; } cv;
    cv.h = __float2bfloat16(f);
    return cv.u;
}

// LDS 64x64 bf16 tiles, row stride 64 elems (128B), XOR swizzle on 8-elem (16B) blocks
__device__ __forceinline__ bf16x8 ld8(const u16* buf, int row, int ecol) {
    int idx = (row << 6) + (ecol ^ ((row & 7) << 3));
    return *reinterpret_cast<const bf16x8*>(buf + idx);
}
__device__ __forceinline__ void st1(u16* buf, int row, int ecol, u16 v) {
    buf[(row << 6) + (ecol ^ ((row & 7) << 3))] = v;
}
__device__ __forceinline__ void st4(u16* buf, int row, int ecol, u16 a, u16 b, u16 c, u16 d) {
    int idx = (row << 6) + (ecol ^ ((row & 7) << 3));
    *reinterpret_cast<ushort4*>(buf + idx) = make_ushort4(a, b, c, d);
}

// wb rows 0..63   = G  = Wq^T Wk / 8   (S = X^T G X)
// wb rows 64..127 = Wf = Wp @ Wv       (Y = (Wf X) P^T)
__global__ void prep_weights(const float* __restrict__ wqkv, const float* __restrict__ wp,
                             u16* __restrict__ wb) {
    int t = blockIdx.x * 256 + threadIdx.x;   // 0 .. 128*64-1
    if (t >= 128 * 64) return;
    int o = t >> 6;
    int c = t & 63;
    float s = 0.0f;
    if (o < 64) {
        for (int m = 0; m < 64; ++m)
            s += wqkv[m * 64 + o] * wqkv[(64 + m) * 64 + c];
        s *= 0.125f;
    } else {
        int of = o - 64;
        if (of < CIN)
            for (int m = 0; m < 64; ++m)
                s += wp[of * 64 + m] * wqkv[(128 + m) * 64 + c];
    }
    wb[t] = f2b(s);
}

// 2-barrier schedule: wave-private staging (own 16 rows) -> GEMM1-T -> B1 ->
// GEMM2 || F-GEMM -> softmax/P -> B2 -> GEMM3. 24 KB LDS, 6 blocks/CU.
__global__ __launch_bounds__(256, 6) void win_attn(
    const float* __restrict__ x, const u16* __restrict__ wb,
    const float* __restrict__ bproj, float* __restrict__ out)
{
    __shared__ __align__(16) u16 t0[64 * 64];  // X[p][c] (own-row staged) -> P[i][j]
    __shared__ __align__(16) u16 t1[64 * 64];  // T[j][a]
    __shared__ __align__(16) u16 t2[64 * 64];  // F[co][j]

    const int tid  = threadIdx.x;
    const int lane = tid & 63;
    const int wid  = tid >> 6;
    const int lr   = lane & 15;
    const int lg   = lane >> 4;

    // XCD swizzle: each XCD gets one batch image (1024 consecutive windows)
    const int win = ((blockIdx.x & 7) << 10) | (blockIdx.x >> 3);
    const int b   = win >> 10;
    const int rem = win & 1023;
    const int hn  = rem >> 5;
    const int wn  = rem & 31;
    const int h0  = hn * 7, w0 = wn * 7;

    const size_t plane = (size_t)HW * HW;

    // this wave's pixel (t0/t1 own row; GEMM1 B-col, GEMM2 A-row, F-GEMM B-col)
    const int prow  = wid * 16 + lr;
    const bool valid = prow < NPIX;
    const int dh = prow / 7, dw = prow - dh * 7;
    const int h = h0 + dh, w = w0 + dw;
    const float cx = -1.0f + (2.0f / 223.0f) * (float)w;
    const float cy = -1.0f + (2.0f / 223.0f) * (float)h;
    const float* xp = x + (size_t)b * CIN * plane + (size_t)h * HW + w;

    // ---- stage own 16 rows of X (wave-private: NO block barrier needed).
    // thread (lr,lg) covers channels [lg*16, lg*16+16) of pixel prow.
#pragma unroll
    for (int it = 0; it < 4; ++it) {
        const int c0 = lg * 16 + it * 4;
        u16 pk[4];
#pragma unroll
        for (int k = 0; k < 4; ++k) {
            const int c = c0 + k;
            float v = 0.0f;
            if (valid)
                v = (c < CIN) ? xp[(size_t)c * plane] : ((c == 62) ? cx : cy);
            pk[k] = f2b(v);
        }
        st4(t0, prow, c0, pk[0], pk[1], pk[2], pk[3]);
    }

    // ---- own X fragment (reused as GEMM1 B, GEMM2 A, F-GEMM B)
    bf16x8 xq[2];
    xq[0] = ld8(t0, prow, lg * 8);
    xq[1] = ld8(t0, prow, 32 + lg * 8);

    const f32x4 fz = {0.f, 0.f, 0.f, 0.f};

    // ---- GEMM1-T: T[all a][own 16 px] = G @ X ; scatter -> t1 own rows
    {
        f32x4 a1[4];
#pragma unroll
        for (int m = 0; m < 4; ++m) a1[m] = fz;
#pragma unroll
        for (int ks = 0; ks < 2; ++ks)
#pragma unroll
            for (int m = 0; m < 4; ++m) {
                bf16x8 ag = *reinterpret_cast<const bf16x8*>(
                    wb + (m * 16 + lr) * 64 + ks * 32 + lg * 8);
                a1[m] = __builtin_amdgcn_mfma_f32_16x16x32_bf16(ag, xq[ks], a1[m], 0, 0, 0);
            }
#pragma unroll
        for (int m = 0; m < 4; ++m)
            st4(t1, prow, m * 16 + lg * 4,
                f2b(a1[m][0]), f2b(a1[m][1]), f2b(a1[m][2]), f2b(a1[m][3]));
    }
    __syncthreads();   // B1: T complete (t1 readable by all waves)

    // ---- GEMM2: S[own i][all j] = sum_a X^T[i][a] T[j][a] ; A = xq regs, B = t1
    f32x4 s4[4];
#pragma unroll
    for (int n = 0; n < 4; ++n) s4[n] = fz;
#pragma unroll
    for (int ks = 0; ks < 2; ++ks)
#pragma unroll
        for (int n = 0; n < 4; ++n) {
            bf16x8 bt = ld8(t1, n * 16 + lr, ks * 32 + lg * 8);
            s4[n] = __builtin_amdgcn_mfma_f32_16x16x32_bf16(xq[ks], bt, s4[n], 0, 0, 0);
        }

    // ---- F-GEMM (independent of S; fills the S->softmax latency bubble):
    // F[all co][own px] = Wf @ X ; scatter -> t2 columns prow
    {
        f32x4 a2[4];
#pragma unroll
        for (int m = 0; m < 4; ++m) a2[m] = fz;
#pragma unroll
        for (int ks = 0; ks < 2; ++ks)
#pragma unroll
            for (int m = 0; m < 4; ++m) {
                bf16x8 af = *reinterpret_cast<const bf16x8*>(
                    wb + ((m + 4) * 16 + lr) * 64 + ks * 32 + lg * 8);
                a2[m] = __builtin_amdgcn_mfma_f32_16x16x32_bf16(af, xq[ks], a2[m], 0, 0, 0);
            }
#pragma unroll
        for (int m = 0; m < 4; ++m)
#pragma unroll
            for (int r = 0; r < 4; ++r)
                st1(t2, m * 16 + lg * 4 + r, prow, f2b(a2[m][r]));
    }

    // ---- register softmax on s4; P -> t0 own rows (own X rows dead: xq cached).
    // Padded columns give S[i][j>=49] == 0 exactly, so max can skip the mask
    // (clamps at 0; harmless). Sum keeps the mask.
#pragma unroll
    for (int r = 0; r < 4; ++r) {
        const int i = wid * 16 + lg * 4 + r;
        float v[4], mx = -1e30f;
#pragma unroll
        for (int n = 0; n < 4; ++n) {
            v[n] = s4[n][r];
            mx = fmaxf(mx, v[n]);
        }
        mx = fmaxf(mx, __shfl_xor(mx, 1));
        mx = fmaxf(mx, __shfl_xor(mx, 2));
        mx = fmaxf(mx, __shfl_xor(mx, 4));
        mx = fmaxf(mx, __shfl_xor(mx, 8));
        float e[4], sm = 0.f;
#pragma unroll
        for (int n = 0; n < 4; ++n) {
            int j = n * 16 + lr;
            e[n] = (j < NPIX) ? __expf(v[n] - mx) : 0.f;
            sm += e[n];
        }
        sm += __shfl_xor(sm, 1);
        sm += __shfl_xor(sm, 2);
        sm += __shfl_xor(sm, 4);
        sm += __shfl_xor(sm, 8);
        float sinv = 1.0f / sm;
#pragma unroll
        for (int n = 0; n < 4; ++n)
            st1(t0, i, n * 16 + lr, f2b(e[n] * sinv));
    }
    __syncthreads();   // B2: F (t2) and P (t0) complete

    // ---- GEMM3: Y[own co][all p'] = sum_j F[co][j] P[p'][j] ; A = t2, B = t0
    f32x4 y4[4];
#pragma unroll
    for (int n = 0; n < 4; ++n) y4[n] = fz;
#pragma unroll
    for (int ks = 0; ks < 2; ++ks) {
        bf16x8 af = ld8(t2, wid * 16 + lr, ks * 32 + lg * 8);
#pragma unroll
        for (int n = 0; n < 4; ++n) {
            bf16x8 bp = ld8(t0, n * 16 + lr, ks * 32 + lg * 8);
            y4[n] = __builtin_amdgcn_mfma_f32_16x16x32_bf16(af, bp, y4[n], 0, 0, 0);
        }
    }

    const int cb = wid * 16 + lg * 4;
    float bias[4];
#pragma unroll
    for (int r = 0; r < 4; ++r) bias[r] = (cb + r < CIN) ? bproj[cb + r] : 0.f;
#pragma unroll
    for (int n = 0; n < 4; ++n) {
        int po = n * 16 + lr;
        if (po < NPIX) {
            int dho = po / 7, dwo = po - dho * 7;
            int ho = h0 + dho, wo = w0 + dwo;
#pragma unroll
            for (int r = 0; r < 4; ++r) {
                int co = cb + r;
                if (co < CIN)
                    out[((b * CIN + co) * HW + ho) * HW + wo] = y4[n][r] + bias[r];
            }
        }
    }
}

extern "C" void kernel_launch(void* const* d_in, const int* in_sizes, int n_in,
                              void* d_out, int out_size, void* d_ws, size_t ws_size,
                              hipStream_t stream) {
    const float* x    = (const float*)d_in[0];
    const float* wqkv = (const float*)d_in[1];
    const float* wp   = (const float*)d_in[2];
    const float* bp   = (const float*)d_in[3];
    float* out = (float*)d_out;

    u16* wb = (u16*)d_ws;   // 128*64 bf16: [G = Wq^T Wk /8 ; Wf = Wp Wv]

    prep_weights<<<32, 256, 0, stream>>>(wqkv, wp, wb);
    win_attn<<<8192, 256, 0, stream>>>(x, wb, bp, out);
}